// Round 1
// 560.096 us; speedup vs baseline: 1.1333x; 1.1333x over previous
//
#include <hip/hip_runtime.h>

#define N_ENT   50000
#define N_REL   500
#define N_EDGES 800000
#define DIM     128
#define BATCH   1024

typedef _Float16 half_t;
typedef __attribute__((ext_vector_type(8))) _Float16 half8;
typedef __attribute__((ext_vector_type(2))) _Float16 half2v;
typedef __attribute__((ext_vector_type(4))) float float4v;
typedef __attribute__((ext_vector_type(2))) float float2v;
typedef __attribute__((ext_vector_type(2))) int int2v;

// ---------------- fused no-dependency work: hist + W1/W2 prep + Wr = R[rel]@W ----------------
__global__ __launch_bounds__(256) void k_pre(
        const int* __restrict__ rows, int* __restrict__ deg,
        const float* __restrict__ W1, const float* __restrict__ W2,
        half_t* __restrict__ W1T_hi, half_t* __restrict__ W1T_lo,
        half_t* __restrict__ W2T_hi, half_t* __restrict__ W2T_lo,
        const float* __restrict__ R_emb, const float* __restrict__ W,
        const int* __restrict__ rel, float* __restrict__ Wr){
    int blk = blockIdx.x;
    if(blk < 3125){
        int e = blk*256 + threadIdx.x;
        if(e < N_EDGES) atomicAdd(&deg[rows[e]], 1);
    } else if(blk < 3253){
        int i = (blk-3125)*256 + threadIdx.x;      // 0..32767
        const float* src = (i < 16384) ? W1 : W2;
        half_t* dh = (i < 16384) ? W1T_hi : W2T_hi;
        half_t* dl = (i < 16384) ? W1T_lo : W2T_lo;
        int j = i & 16383;
        int d = j >> 7, c = j & 127;
        float f = src[j];
        half_t h = (half_t)f;
        dh[c*DIM + d] = h;
        dl[c*DIM + d] = (half_t)(f - (float)h);
    } else {
        // Wr: 512 blocks, 2 batch rows per block (same loop structure as old k_vm)
        __shared__ float rs[2][DIM];
        int half_id = threadIdx.x >> 7;
        int bb = (blk-3253)*2 + half_id;
        int j = threadIdx.x & 127;
        int rid = rel[bb];
        rs[half_id][j] = R_emb[rid*DIM + j];
        __syncthreads();
        float acc = 0.f;
        #pragma unroll 8
        for(int d=0; d<DIM; d++) acc += rs[half_id][d] * W[d*DIM + j];
        Wr[bb*DIM + j] = acc;
    }
}

// ---------------- block 0: prefix scan | blocks 1..196: mm1 = E[init_ind] @ W1 ----------------
__global__ __launch_bounds__(1024) void k_scan_mm1(
        const int* __restrict__ deg, int* __restrict__ row_start,
        const float* __restrict__ E, const int* __restrict__ init_ind,
        const half_t* __restrict__ WT_hi, const half_t* __restrict__ WT_lo,
        half_t* __restrict__ t_out){
    if(blockIdx.x == 0){
        __shared__ int part[1024];
        const int CH = 49;                       // 1024*49 = 50176 >= 50001
        int t = threadIdx.x;
        int base = t*CH;
        int s = 0;
        for(int i=0;i<CH;i++){ int idx=base+i; if(idx<N_ENT) s += deg[idx]; }
        part[t]=s; __syncthreads();
        for(int off=1; off<1024; off<<=1){
            int v = part[t];
            int add = (t>=off)? part[t-off] : 0;
            __syncthreads();
            part[t] = v+add;
            __syncthreads();
        }
        int run = part[t]-s;
        for(int i=0;i<CH;i++){
            int idx=base+i;
            if(idx<=N_ENT){
                row_start[idx]=run;
                if(idx<N_ENT) run += deg[idx];
            }
        }
        return;
    }
    int wave = threadIdx.x >> 6, lane = threadIdx.x & 63;
    int mt = (blockIdx.x-1)*16 + wave;
    if(mt >= 3125) return;
    int m = lane & 15, q = lane >> 4;
    int row = init_ind[mt*16 + m];
    const float* ap = E + (long)row*DIM + q*8;
    float4v acc[8];
    #pragma unroll
    for(int i=0;i<8;i++) acc[i] = (float4v){0.f,0.f,0.f,0.f};
    #pragma unroll
    for(int ks=0; ks<4; ks++){
        float4v u0 = *(const float4v*)(ap + ks*32);
        float4v u1 = *(const float4v*)(ap + ks*32 + 4);
        half8 ah, al;
        #pragma unroll
        for(int j=0;j<8;j++){
            float fv = (j<4) ? u0[j] : u1[j-4];
            half_t h = (half_t)fv;
            ah[j] = h;
            al[j] = (half_t)(fv - (float)h);
        }
        #pragma unroll
        for(int nt=0; nt<8; nt++){
            half8 bh = *(const half8*)(WT_hi + (nt*16 + m)*DIM + ks*32 + q*8);
            half8 bl = *(const half8*)(WT_lo + (nt*16 + m)*DIM + ks*32 + q*8);
            acc[nt] = __builtin_amdgcn_mfma_f32_16x16x32_f16(ah, bh, acc[nt], 0,0,0);
            acc[nt] = __builtin_amdgcn_mfma_f32_16x16x32_f16(ah, bl, acc[nt], 0,0,0);
            acc[nt] = __builtin_amdgcn_mfma_f32_16x16x32_f16(al, bh, acc[nt], 0,0,0);
        }
    }
    #pragma unroll
    for(int nt=0; nt<8; nt++)
        #pragma unroll
        for(int r=0;r<4;r++)
            t_out[(mt*16 + q*4 + r)*DIM + nt*16 + m] = (half_t)acc[nt][r];
}

// ---------------- scatter: paired {col, val} 8B records ----------------
__global__ __launch_bounds__(256) void k_scatter(const int* __restrict__ rows,
        const int* __restrict__ cols, const float* __restrict__ vals,
        const int* __restrict__ row_start, int* __restrict__ cursor,
        int2v* __restrict__ csr){
    int e = blockIdx.x*256 + threadIdx.x;
    if(e >= N_EDGES) return;
    int r = rows[e];
    int pos = row_start[r] + atomicAdd(&cursor[r], 1);
    int2v p;
    p[0] = cols[e];
    p[1] = __float_as_int(vals[e]);
    csr[pos] = p;
}

// ---------------- fused spmm1 + mm2: h tile lives in LDS, never hits HBM ----------------
__global__ __launch_bounds__(256) void k_sp1mm2(
        const half_t* __restrict__ t, const int* __restrict__ row_start,
        const int2v* __restrict__ csr, const float* __restrict__ b1,
        const half_t* __restrict__ WT_hi, const half_t* __restrict__ WT_lo,
        half_t* __restrict__ t2){
    __shared__ half_t hh[16][136];               // +8 halves pad: 2-way (free) bank pattern
    __shared__ half_t hl[16][136];
    int wave = threadIdx.x>>6, lane = threadIdx.x&63;
    int mt = blockIdx.x;                         // 3125 tiles x 16 rows = 50000
    const half2v* tp = (const half2v*)t;
    float2v bb = *(const float2v*)(b1 + lane*2);
    // phase 1: spmm rows mt*16 + wave*4 .. +3 (per-row summation order identical to old k_spmm1)
    for(int rr=0; rr<4; rr++){
        int i = mt*16 + wave*4 + rr;
        int e0 = __builtin_amdgcn_readfirstlane(row_start[i]);
        int e1 = __builtin_amdgcn_readfirstlane(row_start[i+1]);
        float a0=0.f, a1=0.f;
        int e = e0;
        for(; e+8<=e1; e+=8){
            int2v p0=csr[e],   p1=csr[e+1], p2=csr[e+2], p3=csr[e+3];
            int2v p4=csr[e+4], p5=csr[e+5], p6=csr[e+6], p7=csr[e+7];
            half2v g0=tp[p0[0]*64+lane], g1=tp[p1[0]*64+lane], g2=tp[p2[0]*64+lane], g3=tp[p3[0]*64+lane];
            half2v g4=tp[p4[0]*64+lane], g5=tp[p5[0]*64+lane], g6=tp[p6[0]*64+lane], g7=tp[p7[0]*64+lane];
            float v0=__int_as_float(p0[1]), v1=__int_as_float(p1[1]), v2=__int_as_float(p2[1]), v3=__int_as_float(p3[1]);
            float v4=__int_as_float(p4[1]), v5=__int_as_float(p5[1]), v6=__int_as_float(p6[1]), v7=__int_as_float(p7[1]);
            a0 += v0*(float)g0[0]; a1 += v0*(float)g0[1];
            a0 += v1*(float)g1[0]; a1 += v1*(float)g1[1];
            a0 += v2*(float)g2[0]; a1 += v2*(float)g2[1];
            a0 += v3*(float)g3[0]; a1 += v3*(float)g3[1];
            a0 += v4*(float)g4[0]; a1 += v4*(float)g4[1];
            a0 += v5*(float)g5[0]; a1 += v5*(float)g5[1];
            a0 += v6*(float)g6[0]; a1 += v6*(float)g6[1];
            a0 += v7*(float)g7[0]; a1 += v7*(float)g7[1];
        }
        for(; e+4<=e1; e+=4){
            int2v p0=csr[e], p1=csr[e+1], p2=csr[e+2], p3=csr[e+3];
            half2v g0=tp[p0[0]*64+lane], g1=tp[p1[0]*64+lane], g2=tp[p2[0]*64+lane], g3=tp[p3[0]*64+lane];
            float v0=__int_as_float(p0[1]), v1=__int_as_float(p1[1]), v2=__int_as_float(p2[1]), v3=__int_as_float(p3[1]);
            a0 += v0*(float)g0[0]; a1 += v0*(float)g0[1];
            a0 += v1*(float)g1[0]; a1 += v1*(float)g1[1];
            a0 += v2*(float)g2[0]; a1 += v2*(float)g2[1];
            a0 += v3*(float)g3[0]; a1 += v3*(float)g3[1];
        }
        for(; e<e1; e++){
            int2v p = csr[e];
            half2v g = tp[p[0]*64+lane];
            float v = __int_as_float(p[1]);
            a0 += v*(float)g[0]; a1 += v*(float)g[1];
        }
        float r0 = fmaxf(a0 + bb[0], 0.f);
        float r1 = fmaxf(a1 + bb[1], 0.f);
        half_t h0=(half_t)r0, h1=(half_t)r1;
        int row = wave*4 + rr;
        *(half2v*)&hh[row][lane*2] = (half2v){h0, h1};
        *(half2v*)&hl[row][lane*2] = (half2v){(half_t)(r0-(float)h0), (half_t)(r1-(float)h1)};
    }
    __syncthreads();
    // phase 2: mm2 on the 16-row tile; each wave owns 2 of the 8 nt column-tiles
    int m = lane & 15, q = lane >> 4;
    float4v acc[2];
    acc[0] = (float4v){0.f,0.f,0.f,0.f};
    acc[1] = (float4v){0.f,0.f,0.f,0.f};
    #pragma unroll
    for(int ks=0; ks<4; ks++){
        half8 ah = *(const half8*)&hh[m][ks*32 + q*8];
        half8 al = *(const half8*)&hl[m][ks*32 + q*8];
        #pragma unroll
        for(int n=0; n<2; n++){
            int nt = wave*2 + n;
            half8 bh = *(const half8*)(WT_hi + (nt*16 + m)*DIM + ks*32 + q*8);
            half8 bl = *(const half8*)(WT_lo + (nt*16 + m)*DIM + ks*32 + q*8);
            acc[n] = __builtin_amdgcn_mfma_f32_16x16x32_f16(ah, bh, acc[n], 0,0,0);
            acc[n] = __builtin_amdgcn_mfma_f32_16x16x32_f16(ah, bl, acc[n], 0,0,0);
            acc[n] = __builtin_amdgcn_mfma_f32_16x16x32_f16(al, bh, acc[n], 0,0,0);
        }
    }
    #pragma unroll
    for(int n=0; n<2; n++){
        int nt = wave*2 + n;
        #pragma unroll
        for(int r=0;r<4;r++)
            t2[(mt*16 + q*4 + r)*DIM + nt*16 + m] = (half_t)acc[n][r];
    }
}

// ---------------- spmm2 + residual add, paired csr, unroll 8 ----------------
__global__ __launch_bounds__(256) void k_spmm2(const half_t* __restrict__ t,
        const int* __restrict__ row_start, const int2v* __restrict__ csr,
        const float* __restrict__ b2_, const float* __restrict__ E,
        const int* __restrict__ init_ind,
        half_t* __restrict__ fe_hi, half_t* __restrict__ fe_lo){
    int wave = threadIdx.x>>6, lane = threadIdx.x&63;
    int i = blockIdx.x*4 + wave;
    if(i >= N_ENT) return;
    int e0 = __builtin_amdgcn_readfirstlane(row_start[i]);
    int e1 = __builtin_amdgcn_readfirstlane(row_start[i+1]);
    const half2v* tp = (const half2v*)t;
    float a0=0.f, a1=0.f;
    int e = e0;
    for(; e+8<=e1; e+=8){
        int2v p0=csr[e],   p1=csr[e+1], p2=csr[e+2], p3=csr[e+3];
        int2v p4=csr[e+4], p5=csr[e+5], p6=csr[e+6], p7=csr[e+7];
        half2v g0=tp[p0[0]*64+lane], g1=tp[p1[0]*64+lane], g2=tp[p2[0]*64+lane], g3=tp[p3[0]*64+lane];
        half2v g4=tp[p4[0]*64+lane], g5=tp[p5[0]*64+lane], g6=tp[p6[0]*64+lane], g7=tp[p7[0]*64+lane];
        float v0=__int_as_float(p0[1]), v1=__int_as_float(p1[1]), v2=__int_as_float(p2[1]), v3=__int_as_float(p3[1]);
        float v4=__int_as_float(p4[1]), v5=__int_as_float(p5[1]), v6=__int_as_float(p6[1]), v7=__int_as_float(p7[1]);
        a0 += v0*(float)g0[0]; a1 += v0*(float)g0[1];
        a0 += v1*(float)g1[0]; a1 += v1*(float)g1[1];
        a0 += v2*(float)g2[0]; a1 += v2*(float)g2[1];
        a0 += v3*(float)g3[0]; a1 += v3*(float)g3[1];
        a0 += v4*(float)g4[0]; a1 += v4*(float)g4[1];
        a0 += v5*(float)g5[0]; a1 += v5*(float)g5[1];
        a0 += v6*(float)g6[0]; a1 += v6*(float)g6[1];
        a0 += v7*(float)g7[0]; a1 += v7*(float)g7[1];
    }
    for(; e+4<=e1; e+=4){
        int2v p0=csr[e], p1=csr[e+1], p2=csr[e+2], p3=csr[e+3];
        half2v g0=tp[p0[0]*64+lane], g1=tp[p1[0]*64+lane], g2=tp[p2[0]*64+lane], g3=tp[p3[0]*64+lane];
        float v0=__int_as_float(p0[1]), v1=__int_as_float(p1[1]), v2=__int_as_float(p2[1]), v3=__int_as_float(p3[1]);
        a0 += v0*(float)g0[0]; a1 += v0*(float)g0[1];
        a0 += v1*(float)g1[0]; a1 += v1*(float)g1[1];
        a0 += v2*(float)g2[0]; a1 += v2*(float)g2[1];
        a0 += v3*(float)g3[0]; a1 += v3*(float)g3[1];
    }
    for(; e<e1; e++){
        int2v p = csr[e];
        half2v g = tp[p[0]*64+lane];
        float v = __int_as_float(p[1]);
        a0 += v*(float)g[0]; a1 += v*(float)g[1];
    }
    int erow = init_ind[i];
    float2v ev = *(const float2v*)(E + (long)erow*DIM + lane*2);
    float2v bb = *(const float2v*)(b2_ + lane*2);
    float f0 = ev[0] + fmaxf(a0 + bb[0], 0.f);
    float f1 = ev[1] + fmaxf(a1 + bb[1], 0.f);
    half_t h0=(half_t)f0, h1=(half_t)f1;
    half2v hi = {h0, h1};
    half2v lo = {(half_t)(f0-(float)h0), (half_t)(f1-(float)h1)};
    *(half2v*)(fe_hi + (long)i*DIM + lane*2) = hi;
    *(half2v*)(fe_lo + (long)i*DIM + lane*2) = lo;
}

// ---------------- vm = bn1(bn0(final[head]) * Wr), Wr precomputed in k_pre ----------------
__global__ __launch_bounds__(256) void k_vm(const float* __restrict__ Wr,
        const int* __restrict__ head, const half_t* __restrict__ fe_hi,
        const half_t* __restrict__ fe_lo, const float* __restrict__ g0v,
        const float* __restrict__ be0, const float* __restrict__ g1v,
        const float* __restrict__ be1, half_t* __restrict__ vm_hi,
        half_t* __restrict__ vm_lo){
    int idx = blockIdx.x*256 + threadIdx.x;      // 0..131071
    int b = idx >> 7, j = idx & 127;
    int hid = head[b];
    const float inv = rsqrtf(1.f + 1e-5f);
    float fe = (float)fe_hi[(long)hid*DIM+j] + (float)fe_lo[(long)hid*DIM+j];
    float x  = fe * (g0v[j] * inv) + be0[j];
    float vmv = (x * Wr[idx]) * (g1v[j] * inv) + be1[j];
    half_t hi = (half_t)vmv;
    vm_hi[idx] = hi;
    vm_lo[idx] = (half_t)(vmv - (float)hi);
}

// ---------------- big GEMM: out = sigmoid(vm @ fe^T), 2-term fp16, LDS epilogue ----------------
__global__ __launch_bounds__(256) void k_big(const half_t* __restrict__ vm_hi,
        const half_t* __restrict__ vm_lo, const half_t* __restrict__ fe_h,
        float* __restrict__ out){
    __shared__ float sl[16*260];             // 16 rows x 260 stride (pad: conflict-free)
    int wave = threadIdx.x>>6, lane = threadIdx.x&63;
    int m = lane&15, q = lane>>4;
    int b0 = blockIdx.y * 64;                // 64 batch rows per block
    int n0 = blockIdx.x * 256 + wave*64;     // wave covers 64 entity cols
    float4v acc[4][4];
    #pragma unroll
    for(int a=0;a<4;a++)
        #pragma unroll
        for(int b=0;b<4;b++) acc[a][b] = (float4v){0.f,0.f,0.f,0.f};
    #pragma unroll
    for(int ks=0; ks<4; ks++){
        half8 B[4], Ah[4], Al[4];
        #pragma unroll
        for(int nt=0;nt<4;nt++){
            int nr = n0 + nt*16 + m;
            if(nr > N_ENT-1) nr = N_ENT-1;
            B[nt] = *(const half8*)(fe_h + (long)nr*DIM + ks*32 + q*8);
        }
        #pragma unroll
        for(int mt=0;mt<4;mt++){
            long ao = (long)(b0 + mt*16 + m)*DIM + ks*32 + q*8;
            Ah[mt] = *(const half8*)(vm_hi + ao);
            Al[mt] = *(const half8*)(vm_lo + ao);
        }
        #pragma unroll
        for(int mt=0;mt<4;mt++)
            #pragma unroll
            for(int nt=0;nt<4;nt++){
                acc[mt][nt] = __builtin_amdgcn_mfma_f32_16x16x32_f16(Ah[mt], B[nt], acc[mt][nt], 0,0,0);
                acc[mt][nt] = __builtin_amdgcn_mfma_f32_16x16x32_f16(Al[mt], B[nt], acc[mt][nt], 0,0,0);
            }
    }
    int gcol = blockIdx.x*256 + lane*4;
    #pragma unroll
    for(int mt=0; mt<4; mt++){
        if(mt) __syncthreads();
        #pragma unroll
        for(int nt=0;nt<4;nt++)
            #pragma unroll
            for(int r=0;r<4;r++){
                float d = acc[mt][nt][r];
                float s = __fdividef(1.f, 1.f + __expf(-d));
                sl[(q*4+r)*260 + wave*64 + nt*16 + m] = s;
            }
        __syncthreads();
        if(gcol < N_ENT){
            #pragma unroll
            for(int k=0;k<4;k++){
                int lr = wave*4 + k;
                float4v vv = *(const float4v*)&sl[lr*260 + lane*4];
                long off = (long)(b0 + mt*16 + lr)*N_ENT + gcol;
                __builtin_nontemporal_store(vv, (float4v*)(out + off));
            }
        }
    }
}

extern "C" void kernel_launch(void* const* d_in, const int* in_sizes, int n_in,
                              void* d_out, int out_size, void* d_ws, size_t ws_size,
                              hipStream_t stream) {
    const float* E     = (const float*)d_in[0];
    const float* R_emb = (const float*)d_in[1];
    const float* W1    = (const float*)d_in[2];
    const float* b1    = (const float*)d_in[3];
    const float* W2    = (const float*)d_in[4];
    const float* b2_   = (const float*)d_in[5];
    const float* W     = (const float*)d_in[6];
    const float* vals  = (const float*)d_in[7];
    const float* g0v   = (const float*)d_in[8];
    const float* be0   = (const float*)d_in[9];
    const float* g1v   = (const float*)d_in[10];
    const float* be1   = (const float*)d_in[11];
    const int* head    = (const int*)d_in[12];
    const int* rel     = (const int*)d_in[13];
    const int* init_ind= (const int*)d_in[14];
    const int* rows    = (const int*)d_in[15];
    const int* cols    = (const int*)d_in[16];
    float* out = (float*)d_out;

    char* w = (char*)d_ws;
    int*    deg       = (int*)   (w + 0);          // 200,000
    int*    cursor    = (int*)   (w + 200000);     // 200,000
    int*    row_start = (int*)   (w + 400000);     // 200,004
    int2v*  csr       = (int2v*) (w + 600064);     // 6,400,000 (paired {col,val})
    half_t* W1T_hi    = (half_t*)(w + 7000064);
    half_t* W1T_lo    = (half_t*)(w + 7032832);
    half_t* W2T_hi    = (half_t*)(w + 7065600);
    half_t* W2T_lo    = (half_t*)(w + 7098368);
    float*  Wr        = (float*) (w + 7131136);    // 524,288
    half_t* t         = (half_t*)(w + 7655424);    // 12.8 MB
    half_t* t2        = (half_t*)(w + 20455424);   // 12.8 MB
    half_t* fe_hi     = (half_t*)(w + 33255424);   // 12.8 MB
    half_t* fe_lo     = (half_t*)(w + 46055424);   // 12.8 MB
    half_t* vm_hi     = (half_t*)(w + 58855424);   // 262,144
    half_t* vm_lo     = (half_t*)(w + 59117568);   // 262,144
    // end ~59.4 MB

    hipMemsetAsync(deg, 0, 2*N_ENT*sizeof(int), stream);   // deg + cursor
    k_pre      <<<3765, 256, 0, stream>>>(rows, deg, W1, W2, W1T_hi, W1T_lo, W2T_hi, W2T_lo,
                                          R_emb, W, rel, Wr);
    k_scan_mm1 <<<197, 1024, 0, stream>>>(deg, row_start, E, init_ind, W1T_hi, W1T_lo, t);
    k_scatter  <<<3125, 256, 0, stream>>>(rows, cols, vals, row_start, cursor, csr);
    k_sp1mm2   <<<3125, 256, 0, stream>>>(t, row_start, csr, b1, W2T_hi, W2T_lo, t2);
    k_spmm2    <<<12500, 256, 0, stream>>>(t2, row_start, csr, b2_, E, init_ind, fe_hi, fe_lo);
    k_vm       <<<512, 256, 0, stream>>>(Wr, head, fe_hi, fe_lo, g0v, be0, g1v, be1, vm_hi, vm_lo);
    k_big      <<<dim3(196, 16), 256, 0, stream>>>(vm_hi, vm_lo, fe_hi, out);
}

// Round 2
// 557.439 us; speedup vs baseline: 1.1387x; 1.0048x over previous
//
#include <hip/hip_runtime.h>

#define N_ENT   50000
#define N_REL   500
#define N_EDGES 800000
#define DIM     128
#define BATCH   1024

typedef _Float16 half_t;
typedef __attribute__((ext_vector_type(8))) _Float16 half8;
typedef __attribute__((ext_vector_type(2))) _Float16 half2v;
typedef __attribute__((ext_vector_type(4))) float float4v;
typedef __attribute__((ext_vector_type(2))) float float2v;
typedef __attribute__((ext_vector_type(2))) int int2v;

// ---------------- fused no-dependency work: hist + W1/W2 prep + Wr = R[rel]@W ----------------
__global__ __launch_bounds__(256) void k_pre(
        const int* __restrict__ rows, int* __restrict__ deg,
        const float* __restrict__ W1, const float* __restrict__ W2,
        half_t* __restrict__ W1T_hi, half_t* __restrict__ W1T_lo,
        half_t* __restrict__ W2T_hi, half_t* __restrict__ W2T_lo,
        const float* __restrict__ R_emb, const float* __restrict__ W,
        const int* __restrict__ rel, float* __restrict__ Wr){
    int blk = blockIdx.x;
    if(blk < 3125){
        int e = blk*256 + threadIdx.x;
        if(e < N_EDGES) atomicAdd(&deg[rows[e]], 1);
    } else if(blk < 3253){
        int i = (blk-3125)*256 + threadIdx.x;      // 0..32767
        const float* src = (i < 16384) ? W1 : W2;
        half_t* dh = (i < 16384) ? W1T_hi : W2T_hi;
        half_t* dl = (i < 16384) ? W1T_lo : W2T_lo;
        int j = i & 16383;
        int d = j >> 7, c = j & 127;
        float f = src[j];
        half_t h = (half_t)f;
        dh[c*DIM + d] = h;
        dl[c*DIM + d] = (half_t)(f - (float)h);
    } else {
        // Wr: 512 blocks, 2 batch rows per block
        __shared__ float rs[2][DIM];
        int half_id = threadIdx.x >> 7;
        int bb = (blk-3253)*2 + half_id;
        int j = threadIdx.x & 127;
        int rid = rel[bb];
        rs[half_id][j] = R_emb[rid*DIM + j];
        __syncthreads();
        float acc = 0.f;
        #pragma unroll 8
        for(int d=0; d<DIM; d++) acc += rs[half_id][d] * W[d*DIM + j];
        Wr[bb*DIM + j] = acc;
    }
}

// ---------------- block 0: prefix scan | blocks 1..196: mm1 = E[init_ind] @ W1 ----------------
__global__ __launch_bounds__(1024) void k_scan_mm1(
        const int* __restrict__ deg, int* __restrict__ row_start,
        const float* __restrict__ E, const int* __restrict__ init_ind,
        const half_t* __restrict__ WT_hi, const half_t* __restrict__ WT_lo,
        half_t* __restrict__ t_out){
    if(blockIdx.x == 0){
        __shared__ int part[1024];
        const int CH = 49;                       // 1024*49 = 50176 >= 50001
        int t = threadIdx.x;
        int base = t*CH;
        int s = 0;
        for(int i=0;i<CH;i++){ int idx=base+i; if(idx<N_ENT) s += deg[idx]; }
        part[t]=s; __syncthreads();
        for(int off=1; off<1024; off<<=1){
            int v = part[t];
            int add = (t>=off)? part[t-off] : 0;
            __syncthreads();
            part[t] = v+add;
            __syncthreads();
        }
        int run = part[t]-s;
        for(int i=0;i<CH;i++){
            int idx=base+i;
            if(idx<=N_ENT){
                row_start[idx]=run;
                if(idx<N_ENT) run += deg[idx];
            }
        }
        return;
    }
    int wave = threadIdx.x >> 6, lane = threadIdx.x & 63;
    int mt = (blockIdx.x-1)*16 + wave;
    if(mt >= 3125) return;
    int m = lane & 15, q = lane >> 4;
    int row = init_ind[mt*16 + m];
    const float* ap = E + (long)row*DIM + q*8;
    float4v acc[8];
    #pragma unroll
    for(int i=0;i<8;i++) acc[i] = (float4v){0.f,0.f,0.f,0.f};
    #pragma unroll
    for(int ks=0; ks<4; ks++){
        float4v u0 = *(const float4v*)(ap + ks*32);
        float4v u1 = *(const float4v*)(ap + ks*32 + 4);
        half8 ah, al;
        #pragma unroll
        for(int j=0;j<8;j++){
            float fv = (j<4) ? u0[j] : u1[j-4];
            half_t h = (half_t)fv;
            ah[j] = h;
            al[j] = (half_t)(fv - (float)h);
        }
        #pragma unroll
        for(int nt=0; nt<8; nt++){
            half8 bh = *(const half8*)(WT_hi + (nt*16 + m)*DIM + ks*32 + q*8);
            half8 bl = *(const half8*)(WT_lo + (nt*16 + m)*DIM + ks*32 + q*8);
            acc[nt] = __builtin_amdgcn_mfma_f32_16x16x32_f16(ah, bh, acc[nt], 0,0,0);
            acc[nt] = __builtin_amdgcn_mfma_f32_16x16x32_f16(ah, bl, acc[nt], 0,0,0);
            acc[nt] = __builtin_amdgcn_mfma_f32_16x16x32_f16(al, bh, acc[nt], 0,0,0);
        }
    }
    #pragma unroll
    for(int nt=0; nt<8; nt++)
        #pragma unroll
        for(int r=0;r<4;r++)
            t_out[(mt*16 + q*4 + r)*DIM + nt*16 + m] = (half_t)acc[nt][r];
}

// ---------------- scatter: paired {col, val} 8B records ----------------
__global__ __launch_bounds__(256) void k_scatter(const int* __restrict__ rows,
        const int* __restrict__ cols, const float* __restrict__ vals,
        const int* __restrict__ row_start, int* __restrict__ cursor,
        int2v* __restrict__ csr){
    int e = blockIdx.x*256 + threadIdx.x;
    if(e >= N_EDGES) return;
    int r = rows[e];
    int pos = row_start[r] + atomicAdd(&cursor[r], 1);
    int2v p;
    p[0] = cols[e];
    p[1] = __float_as_int(vals[e]);
    csr[pos] = p;
}

// ---------------- fused spmm1 + mm2: 16 waves, ONE row per wave (max gather MLP) ----------------
__global__ __launch_bounds__(1024) void k_sp1mm2(
        const half_t* __restrict__ t, const int* __restrict__ row_start,
        const int2v* __restrict__ csr, const float* __restrict__ b1,
        const half_t* __restrict__ WT_hi, const half_t* __restrict__ WT_lo,
        half_t* __restrict__ t2){
    __shared__ half_t hh[16][136];               // +8 halves pad
    __shared__ half_t hl[16][136];
    int wave = threadIdx.x>>6, lane = threadIdx.x&63;
    int mt = blockIdx.x;                         // 3125 tiles x 16 rows = 50000
    const half2v* tp = (const half2v*)t;
    float2v bb = *(const float2v*)(b1 + lane*2);
    // phase 1: each wave owns row mt*16 + wave (per-row summation order unchanged)
    {
        int i = mt*16 + wave;
        int e0 = __builtin_amdgcn_readfirstlane(row_start[i]);
        int e1 = __builtin_amdgcn_readfirstlane(row_start[i+1]);
        float a0=0.f, a1=0.f;
        int e = e0;
        for(; e+8<=e1; e+=8){
            int2v p0=csr[e],   p1=csr[e+1], p2=csr[e+2], p3=csr[e+3];
            int2v p4=csr[e+4], p5=csr[e+5], p6=csr[e+6], p7=csr[e+7];
            half2v g0=tp[p0[0]*64+lane], g1=tp[p1[0]*64+lane], g2=tp[p2[0]*64+lane], g3=tp[p3[0]*64+lane];
            half2v g4=tp[p4[0]*64+lane], g5=tp[p5[0]*64+lane], g6=tp[p6[0]*64+lane], g7=tp[p7[0]*64+lane];
            float v0=__int_as_float(p0[1]), v1=__int_as_float(p1[1]), v2=__int_as_float(p2[1]), v3=__int_as_float(p3[1]);
            float v4=__int_as_float(p4[1]), v5=__int_as_float(p5[1]), v6=__int_as_float(p6[1]), v7=__int_as_float(p7[1]);
            a0 += v0*(float)g0[0]; a1 += v0*(float)g0[1];
            a0 += v1*(float)g1[0]; a1 += v1*(float)g1[1];
            a0 += v2*(float)g2[0]; a1 += v2*(float)g2[1];
            a0 += v3*(float)g3[0]; a1 += v3*(float)g3[1];
            a0 += v4*(float)g4[0]; a1 += v4*(float)g4[1];
            a0 += v5*(float)g5[0]; a1 += v5*(float)g5[1];
            a0 += v6*(float)g6[0]; a1 += v6*(float)g6[1];
            a0 += v7*(float)g7[0]; a1 += v7*(float)g7[1];
        }
        for(; e+4<=e1; e+=4){
            int2v p0=csr[e], p1=csr[e+1], p2=csr[e+2], p3=csr[e+3];
            half2v g0=tp[p0[0]*64+lane], g1=tp[p1[0]*64+lane], g2=tp[p2[0]*64+lane], g3=tp[p3[0]*64+lane];
            float v0=__int_as_float(p0[1]), v1=__int_as_float(p1[1]), v2=__int_as_float(p2[1]), v3=__int_as_float(p3[1]);
            a0 += v0*(float)g0[0]; a1 += v0*(float)g0[1];
            a0 += v1*(float)g1[0]; a1 += v1*(float)g1[1];
            a0 += v2*(float)g2[0]; a1 += v2*(float)g2[1];
            a0 += v3*(float)g3[0]; a1 += v3*(float)g3[1];
        }
        for(; e<e1; e++){
            int2v p = csr[e];
            half2v g = tp[p[0]*64+lane];
            float v = __int_as_float(p[1]);
            a0 += v*(float)g[0]; a1 += v*(float)g[1];
        }
        float r0 = fmaxf(a0 + bb[0], 0.f);
        float r1 = fmaxf(a1 + bb[1], 0.f);
        half_t h0=(half_t)r0, h1=(half_t)r1;
        *(half2v*)&hh[wave][lane*2] = (half2v){h0, h1};
        *(half2v*)&hl[wave][lane*2] = (half2v){(half_t)(r0-(float)h0), (half_t)(r1-(float)h1)};
    }
    __syncthreads();
    // phase 2: mm2 on the 16-row tile; waves 0..7 each own one nt column-tile
    if(wave < 8){
        int m = lane & 15, q = lane >> 4;
        int nt = wave;
        float4v acc = (float4v){0.f,0.f,0.f,0.f};
        #pragma unroll
        for(int ks=0; ks<4; ks++){
            half8 ah = *(const half8*)&hh[m][ks*32 + q*8];
            half8 al = *(const half8*)&hl[m][ks*32 + q*8];
            half8 bh = *(const half8*)(WT_hi + (nt*16 + m)*DIM + ks*32 + q*8);
            half8 bl = *(const half8*)(WT_lo + (nt*16 + m)*DIM + ks*32 + q*8);
            acc = __builtin_amdgcn_mfma_f32_16x16x32_f16(ah, bh, acc, 0,0,0);
            acc = __builtin_amdgcn_mfma_f32_16x16x32_f16(ah, bl, acc, 0,0,0);
            acc = __builtin_amdgcn_mfma_f32_16x16x32_f16(al, bh, acc, 0,0,0);
        }
        #pragma unroll
        for(int r=0;r<4;r++)
            t2[(mt*16 + q*4 + r)*DIM + nt*16 + m] = (half_t)acc[r];
    }
}

// ---------------- spmm2 + residual add, paired csr, unroll 8 ----------------
__global__ __launch_bounds__(256) void k_spmm2(const half_t* __restrict__ t,
        const int* __restrict__ row_start, const int2v* __restrict__ csr,
        const float* __restrict__ b2_, const float* __restrict__ E,
        const int* __restrict__ init_ind,
        half_t* __restrict__ fe_hi, half_t* __restrict__ fe_lo){
    int wave = threadIdx.x>>6, lane = threadIdx.x&63;
    int i = blockIdx.x*4 + wave;
    if(i >= N_ENT) return;
    int e0 = __builtin_amdgcn_readfirstlane(row_start[i]);
    int e1 = __builtin_amdgcn_readfirstlane(row_start[i+1]);
    const half2v* tp = (const half2v*)t;
    float a0=0.f, a1=0.f;
    int e = e0;
    for(; e+8<=e1; e+=8){
        int2v p0=csr[e],   p1=csr[e+1], p2=csr[e+2], p3=csr[e+3];
        int2v p4=csr[e+4], p5=csr[e+5], p6=csr[e+6], p7=csr[e+7];
        half2v g0=tp[p0[0]*64+lane], g1=tp[p1[0]*64+lane], g2=tp[p2[0]*64+lane], g3=tp[p3[0]*64+lane];
        half2v g4=tp[p4[0]*64+lane], g5=tp[p5[0]*64+lane], g6=tp[p6[0]*64+lane], g7=tp[p7[0]*64+lane];
        float v0=__int_as_float(p0[1]), v1=__int_as_float(p1[1]), v2=__int_as_float(p2[1]), v3=__int_as_float(p3[1]);
        float v4=__int_as_float(p4[1]), v5=__int_as_float(p5[1]), v6=__int_as_float(p6[1]), v7=__int_as_float(p7[1]);
        a0 += v0*(float)g0[0]; a1 += v0*(float)g0[1];
        a0 += v1*(float)g1[0]; a1 += v1*(float)g1[1];
        a0 += v2*(float)g2[0]; a1 += v2*(float)g2[1];
        a0 += v3*(float)g3[0]; a1 += v3*(float)g3[1];
        a0 += v4*(float)g4[0]; a1 += v4*(float)g4[1];
        a0 += v5*(float)g5[0]; a1 += v5*(float)g5[1];
        a0 += v6*(float)g6[0]; a1 += v6*(float)g6[1];
        a0 += v7*(float)g7[0]; a1 += v7*(float)g7[1];
    }
    for(; e+4<=e1; e+=4){
        int2v p0=csr[e], p1=csr[e+1], p2=csr[e+2], p3=csr[e+3];
        half2v g0=tp[p0[0]*64+lane], g1=tp[p1[0]*64+lane], g2=tp[p2[0]*64+lane], g3=tp[p3[0]*64+lane];
        float v0=__int_as_float(p0[1]), v1=__int_as_float(p1[1]), v2=__int_as_float(p2[1]), v3=__int_as_float(p3[1]);
        a0 += v0*(float)g0[0]; a1 += v0*(float)g0[1];
        a0 += v1*(float)g1[0]; a1 += v1*(float)g1[1];
        a0 += v2*(float)g2[0]; a1 += v2*(float)g2[1];
        a0 += v3*(float)g3[0]; a1 += v3*(float)g3[1];
    }
    for(; e<e1; e++){
        int2v p = csr[e];
        half2v g = tp[p[0]*64+lane];
        float v = __int_as_float(p[1]);
        a0 += v*(float)g[0]; a1 += v*(float)g[1];
    }
    int erow = init_ind[i];
    float2v ev = *(const float2v*)(E + (long)erow*DIM + lane*2);
    float2v bb = *(const float2v*)(b2_ + lane*2);
    float f0 = ev[0] + fmaxf(a0 + bb[0], 0.f);
    float f1 = ev[1] + fmaxf(a1 + bb[1], 0.f);
    half_t h0=(half_t)f0, h1=(half_t)f1;
    half2v hi = {h0, h1};
    half2v lo = {(half_t)(f0-(float)h0), (half_t)(f1-(float)h1)};
    *(half2v*)(fe_hi + (long)i*DIM + lane*2) = hi;
    *(half2v*)(fe_lo + (long)i*DIM + lane*2) = lo;
}

// ---------------- vm = bn1(bn0(final[head]) * Wr) ----------------
__global__ __launch_bounds__(256) void k_vm(const float* __restrict__ Wr,
        const int* __restrict__ head, const half_t* __restrict__ fe_hi,
        const half_t* __restrict__ fe_lo, const float* __restrict__ g0v,
        const float* __restrict__ be0, const float* __restrict__ g1v,
        const float* __restrict__ be1, half_t* __restrict__ vm_hi,
        half_t* __restrict__ vm_lo){
    int idx = blockIdx.x*256 + threadIdx.x;      // 0..131071
    int b = idx >> 7, j = idx & 127;
    int hid = head[b];
    const float inv = rsqrtf(1.f + 1e-5f);
    float fe = (float)fe_hi[(long)hid*DIM+j] + (float)fe_lo[(long)hid*DIM+j];
    float x  = fe * (g0v[j] * inv) + be0[j];
    float vmv = (x * Wr[idx]) * (g1v[j] * inv) + be1[j];
    half_t hi = (half_t)vmv;
    vm_hi[idx] = hi;
    vm_lo[idx] = (half_t)(vmv - (float)hi);
}

// ---------------- big GEMM: out = sigmoid(vm @ fe^T), XCD-swizzled for fe L2 residency ----------------
__global__ __launch_bounds__(256) void k_big(const half_t* __restrict__ vm_hi,
        const half_t* __restrict__ vm_lo, const half_t* __restrict__ fe_h,
        float* __restrict__ out){
    __shared__ float sl[16*260];             // 16 rows x 260 stride (pad: conflict-free)
    // bijective XCD swizzle: 3136 blocks, q=392 exact. Each XCD owns a contiguous
    // 25-panel slice of fe (1.6 MB, L2-resident) and iterates by (batch tiles) fastest.
    int flat = blockIdx.x;
    int wg = (flat & 7)*392 + (flat >> 3);
    int bx = wg >> 4;                        // 0..195  entity-panel index
    int by = wg & 15;                        // 0..15   batch-tile index
    int wave = threadIdx.x>>6, lane = threadIdx.x&63;
    int m = lane&15, q = lane>>4;
    int b0 = by * 64;                        // 64 batch rows per block
    int n0 = bx * 256 + wave*64;             // wave covers 64 entity cols
    float4v acc[4][4];
    #pragma unroll
    for(int a=0;a<4;a++)
        #pragma unroll
        for(int b=0;b<4;b++) acc[a][b] = (float4v){0.f,0.f,0.f,0.f};
    #pragma unroll
    for(int ks=0; ks<4; ks++){
        half8 B[4], Ah[4], Al[4];
        #pragma unroll
        for(int nt=0;nt<4;nt++){
            int nr = n0 + nt*16 + m;
            if(nr > N_ENT-1) nr = N_ENT-1;
            B[nt] = *(const half8*)(fe_h + (long)nr*DIM + ks*32 + q*8);
        }
        #pragma unroll
        for(int mt=0;mt<4;mt++){
            long ao = (long)(b0 + mt*16 + m)*DIM + ks*32 + q*8;
            Ah[mt] = *(const half8*)(vm_hi + ao);
            Al[mt] = *(const half8*)(vm_lo + ao);
        }
        #pragma unroll
        for(int mt=0;mt<4;mt++)
            #pragma unroll
            for(int nt=0;nt<4;nt++){
                acc[mt][nt] = __builtin_amdgcn_mfma_f32_16x16x32_f16(Ah[mt], B[nt], acc[mt][nt], 0,0,0);
                acc[mt][nt] = __builtin_amdgcn_mfma_f32_16x16x32_f16(Al[mt], B[nt], acc[mt][nt], 0,0,0);
            }
    }
    int gcol = bx*256 + lane*4;
    #pragma unroll
    for(int mt=0; mt<4; mt++){
        if(mt) __syncthreads();
        #pragma unroll
        for(int nt=0;nt<4;nt++)
            #pragma unroll
            for(int r=0;r<4;r++){
                float d = acc[mt][nt][r];
                float s = __fdividef(1.f, 1.f + __expf(-d));
                sl[(q*4+r)*260 + wave*64 + nt*16 + m] = s;
            }
        __syncthreads();
        if(gcol < N_ENT){
            #pragma unroll
            for(int k=0;k<4;k++){
                int lr = wave*4 + k;
                float4v vv = *(const float4v*)&sl[lr*260 + lane*4];
                long off = (long)(b0 + mt*16 + lr)*N_ENT + gcol;
                __builtin_nontemporal_store(vv, (float4v*)(out + off));
            }
        }
    }
}

extern "C" void kernel_launch(void* const* d_in, const int* in_sizes, int n_in,
                              void* d_out, int out_size, void* d_ws, size_t ws_size,
                              hipStream_t stream) {
    const float* E     = (const float*)d_in[0];
    const float* R_emb = (const float*)d_in[1];
    const float* W1    = (const float*)d_in[2];
    const float* b1    = (const float*)d_in[3];
    const float* W2    = (const float*)d_in[4];
    const float* b2_   = (const float*)d_in[5];
    const float* W     = (const float*)d_in[6];
    const float* vals  = (const float*)d_in[7];
    const float* g0v   = (const float*)d_in[8];
    const float* be0   = (const float*)d_in[9];
    const float* g1v   = (const float*)d_in[10];
    const float* be1   = (const float*)d_in[11];
    const int* head    = (const int*)d_in[12];
    const int* rel     = (const int*)d_in[13];
    const int* init_ind= (const int*)d_in[14];
    const int* rows    = (const int*)d_in[15];
    const int* cols    = (const int*)d_in[16];
    float* out = (float*)d_out;

    char* w = (char*)d_ws;
    int*    deg       = (int*)   (w + 0);          // 200,000
    int*    cursor    = (int*)   (w + 200000);     // 200,000
    int*    row_start = (int*)   (w + 400000);     // 200,004
    int2v*  csr       = (int2v*) (w + 600064);     // 6,400,000 (paired {col,val})
    half_t* W1T_hi    = (half_t*)(w + 7000064);
    half_t* W1T_lo    = (half_t*)(w + 7032832);
    half_t* W2T_hi    = (half_t*)(w + 7065600);
    half_t* W2T_lo    = (half_t*)(w + 7098368);
    float*  Wr        = (float*) (w + 7131136);    // 524,288
    half_t* t         = (half_t*)(w + 7655424);    // 12.8 MB
    half_t* t2        = (half_t*)(w + 20455424);   // 12.8 MB
    half_t* fe_hi     = (half_t*)(w + 33255424);   // 12.8 MB
    half_t* fe_lo     = (half_t*)(w + 46055424);   // 12.8 MB
    half_t* vm_hi     = (half_t*)(w + 58855424);   // 262,144
    half_t* vm_lo     = (half_t*)(w + 59117568);   // 262,144
    // end ~59.4 MB

    hipMemsetAsync(deg, 0, 2*N_ENT*sizeof(int), stream);   // deg + cursor
    k_pre      <<<3765, 256, 0, stream>>>(rows, deg, W1, W2, W1T_hi, W1T_lo, W2T_hi, W2T_lo,
                                          R_emb, W, rel, Wr);
    k_scan_mm1 <<<197, 1024, 0, stream>>>(deg, row_start, E, init_ind, W1T_hi, W1T_lo, t);
    k_scatter  <<<3125, 256, 0, stream>>>(rows, cols, vals, row_start, cursor, csr);
    k_sp1mm2   <<<3125, 1024, 0, stream>>>(t, row_start, csr, b1, W2T_hi, W2T_lo, t2);
    k_spmm2    <<<12500, 256, 0, stream>>>(t2, row_start, csr, b2_, E, init_ind, fe_hi, fe_lo);
    k_vm       <<<512, 256, 0, stream>>>(Wr, head, fe_hi, fe_lo, g0v, be0, g1v, be1, vm_hi, vm_lo);
    k_big      <<<3136, 256, 0, stream>>>(vm_hi, vm_lo, fe_hi, out);
}